// Round 11
// baseline (433.646 us; speedup 1.0000x reference)
//
#include <hip/hip_runtime.h>
#include <cstdint>
#include <cstddef>

#define HNUM 8
#define HDIM 64
#define WIN 512
#define RATIO 8
#define TOPKN 64
#define BATCH 2
#define SEQ 2048
#define DM 512
#define NPOOLS 192

typedef unsigned short u16;
typedef __attribute__((ext_vector_type(8))) short bf16x8;
typedef __attribute__((ext_vector_type(4))) float f32x4;

static __device__ __forceinline__ int imaxi(int a, int b){ return a > b ? a : b; }
static __device__ __forceinline__ int imini(int a, int b){ return a < b ? a : b; }

static __device__ __forceinline__ u16 f2bf(float v) {
    union { float f; uint32_t u; } c; c.f = v;
    uint32_t r = c.u + 0x7fffu + ((c.u >> 16) & 1u);
    return (u16)(r >> 16);
}
static __device__ __forceinline__ float bf2f(u16 u) {
    union { uint32_t u; float f; } c; c.u = ((uint32_t)u) << 16;
    return c.f;
}

// ---------------- fp32 -> (hi, lo) bf16 planes, elementwise ----------------
__global__ __launch_bounds__(256)
void conv_act(const float* __restrict__ in, u16* __restrict__ h, u16* __restrict__ l, int n8)
{
    int i = blockIdx.x * 256 + threadIdx.x;
    if (i >= n8) return;
    const float4* p = (const float4*)(in + (size_t)i * 8);
    float4 a = p[0], b = p[1];
    float v[8] = {a.x, a.y, a.z, a.w, b.x, b.y, b.z, b.w};
    u16 hs[8], ls[8];
    #pragma unroll
    for (int j = 0; j < 8; ++j) {
        hs[j] = f2bf(v[j]);
        ls[j] = f2bf(v[j] - bf2f(hs[j]));
    }
    *(uint4*)(h + (size_t)i * 8) = *(uint4*)hs;
    *(uint4*)(l + (size_t)i * 8) = *(uint4*)ls;
}

// ------------- weight transpose-convert: W[512][N] -> WT planes [N][512] -------------
__global__ __launch_bounds__(256)
void conv_wT(const float* __restrict__ W, int N,
             u16* __restrict__ WTh, u16* __restrict__ WTl, int dstRowOff)
{
    __shared__ float t[64][65];
    const int n0 = blockIdx.x * 64, k0 = blockIdx.y * 64;
    const int tid = threadIdx.x;
    const int tk = tid >> 4, tn = (tid & 15) * 4;
    #pragma unroll
    for (int r = 0; r < 4; ++r) {
        int k = tk + r * 16;
        float4 v = *(const float4*)(W + (size_t)(k0 + k) * N + n0 + tn);
        t[k][tn + 0] = v.x; t[k][tn + 1] = v.y; t[k][tn + 2] = v.z; t[k][tn + 3] = v.w;
    }
    __syncthreads();
    const int nl = tid >> 2, s = tid & 3;
    u16 hs[16], ls[16];
    #pragma unroll
    for (int j = 0; j < 16; ++j) {
        float v = t[s * 16 + j][nl];
        hs[j] = f2bf(v);
        ls[j] = f2bf(v - bf2f(hs[j]));
    }
    size_t base = (size_t)(dstRowOff + n0 + nl) * 512 + k0 + s * 16;
    *(uint4*)(WTh + base)     = ((uint4*)hs)[0];
    *(uint4*)(WTh + base + 8) = ((uint4*)hs)[1];
    *(uint4*)(WTl + base)     = ((uint4*)ls)[0];
    *(uint4*)(WTl + base + 8) = ((uint4*)ls)[1];
}

// ------------- 11x (512x512) weight transpose-convert in one launch -------------
// z0-1: cq,tq -> Wq2T rows 0/512 ; z2-3: gc,gt -> Wg2T rows 0/512 ;
// z4-6: lout,cout,tout ; z7-10: ck,cv,tk,tv -> WkvT rows (z-7)*512
__global__ __launch_bounds__(256)
void conv_wT11(const float* __restrict__ w0, const float* __restrict__ w1,
               const float* __restrict__ w2, const float* __restrict__ w3,
               const float* __restrict__ w4, const float* __restrict__ w5,
               const float* __restrict__ w6, const float* __restrict__ w7,
               const float* __restrict__ w8, const float* __restrict__ w9,
               const float* __restrict__ w10,
               u16* __restrict__ Wq2Th, u16* __restrict__ Wq2Tl,
               u16* __restrict__ Wg2Th, u16* __restrict__ Wg2Tl,
               u16* __restrict__ WLoTh, u16* __restrict__ WLoTl,
               u16* __restrict__ WCoTh, u16* __restrict__ WCoTl,
               u16* __restrict__ WToTh, u16* __restrict__ WToTl,
               u16* __restrict__ WkvTh, u16* __restrict__ WkvTl)
{
    const float* W; u16* dh; u16* dl; int rowoff = 0;
    switch (blockIdx.z) {
        case 0:  W = w0;  dh = Wq2Th; dl = Wq2Tl; rowoff = 0;    break;
        case 1:  W = w1;  dh = Wq2Th; dl = Wq2Tl; rowoff = 512;  break;
        case 2:  W = w2;  dh = Wg2Th; dl = Wg2Tl; rowoff = 0;    break;
        case 3:  W = w3;  dh = Wg2Th; dl = Wg2Tl; rowoff = 512;  break;
        case 4:  W = w4;  dh = WLoTh; dl = WLoTl; rowoff = 0;    break;
        case 5:  W = w5;  dh = WCoTh; dl = WCoTl; rowoff = 0;    break;
        case 6:  W = w6;  dh = WToTh; dl = WToTl; rowoff = 0;    break;
        case 7:  W = w7;  dh = WkvTh; dl = WkvTl; rowoff = 0;    break;
        case 8:  W = w8;  dh = WkvTh; dl = WkvTl; rowoff = 512;  break;
        case 9:  W = w9;  dh = WkvTh; dl = WkvTl; rowoff = 1024; break;
        default: W = w10; dh = WkvTh; dl = WkvTl; rowoff = 1536; break;
    }
    __shared__ float t[64][65];
    const int n0 = blockIdx.x * 64, k0 = blockIdx.y * 64;
    const int tid = threadIdx.x;
    const int tk = tid >> 4, tn = (tid & 15) * 4;
    #pragma unroll
    for (int r = 0; r < 4; ++r) {
        int k = tk + r * 16;
        float4 v = *(const float4*)(W + (size_t)(k0 + k) * 512 + n0 + tn);
        t[k][tn + 0] = v.x; t[k][tn + 1] = v.y; t[k][tn + 2] = v.z; t[k][tn + 3] = v.w;
    }
    __syncthreads();
    const int nl = tid >> 2, s = tid & 3;
    u16 hs[16], ls[16];
    #pragma unroll
    for (int j = 0; j < 16; ++j) {
        float v = t[s * 16 + j][nl];
        hs[j] = f2bf(v);
        ls[j] = f2bf(v - bf2f(hs[j]));
    }
    size_t base = (size_t)(rowoff + n0 + nl) * 512 + k0 + s * 16;
    *(uint4*)(dh + base)     = ((uint4*)hs)[0];
    *(uint4*)(dh + base + 8) = ((uint4*)hs)[1];
    *(uint4*)(dl + base)     = ((uint4*)ls)[0];
    *(uint4*)(dl + base + 8) = ((uint4*)ls)[1];
}

// ---------------- all bias concats in one launch ----------------
__global__ void bcat_all(const float* __restrict__ cq_b, const float* __restrict__ tq_b,
                         const float* __restrict__ gc_b, const float* __restrict__ gt_b,
                         const float* __restrict__ ck_b, const float* __restrict__ cv_b,
                         const float* __restrict__ tk_b, const float* __restrict__ tv_b,
                         float* __restrict__ bq2, float* __restrict__ bg2, float* __restrict__ bkv)
{
    int i = blockIdx.x * 256 + threadIdx.x;
    if (i < 512) bq2[i] = cq_b[i];
    else if (i < 1024) bq2[i] = tq_b[i - 512];
    else if (i < 1536) bg2[i - 1024] = gc_b[i - 1024];
    else if (i < 2048) bg2[i - 1024] = gt_b[i - 1536];
    else if (i < 2560) bkv[i - 2048] = ck_b[i - 2048];
    else if (i < 3072) bkv[i - 2048] = cv_b[i - 2560];
    else if (i < 3584) bkv[i - 2048] = tk_b[i - 3072];
    else if (i < 4096) bkv[i - 2048] = tv_b[i - 3584];
}

// ---------------- split-bf16 MFMA GEMM: tile 128x128, K=512 ----------------
// MODE 0: C = A@B + bias (fp32)
// MODE 1: C += sigmoid(G) * (A@B + bias)
// MODE 2: planes out: (Ch,Cl) = split((A@B+bias) * (col<scaleCols ? 0.125 : 1))
template<int MODE>
__global__ __launch_bounds__(256)
void gemm_mfma(const u16* __restrict__ Ah, const u16* __restrict__ Al,
               const u16* __restrict__ BTh, const u16* __restrict__ BTl,
               const float* __restrict__ bias, float* __restrict__ C,
               u16* __restrict__ Ch, u16* __restrict__ Cl,
               const float* __restrict__ G, int gstride, int N, int scaleCols)
{
    __shared__ __align__(16) u16 AsH[128 * 40], AsL[128 * 40], BsH[128 * 40], BsL[128 * 40];
    const int tid = threadIdx.x;
    const int m0 = blockIdx.y * 128, n0 = blockIdx.x * 128;
    const int wid = tid >> 6, lane = tid & 63;
    const int wm = (wid >> 1) * 64, wn = (wid & 1) * 64;
    const int lr = lane & 15, lg = lane >> 4;

    f32x4 acc[4][4];
    #pragma unroll
    for (int i = 0; i < 4; ++i)
        #pragma unroll
        for (int j = 0; j < 4; ++j) acc[i][j] = (f32x4){0.f, 0.f, 0.f, 0.f};

    const int r0 = tid >> 2, s = tid & 3;

    for (int k0 = 0; k0 < 512; k0 += 32) {
        __syncthreads();
        size_t ga = (size_t)(m0 + r0) * 512 + k0 + s * 8;
        *(uint4*)&AsH[r0 * 40 + s * 8] = *(const uint4*)(Ah + ga);
        *(uint4*)&AsL[r0 * 40 + s * 8] = *(const uint4*)(Al + ga);
        size_t ga2 = (size_t)(m0 + r0 + 64) * 512 + k0 + s * 8;
        *(uint4*)&AsH[(r0 + 64) * 40 + s * 8] = *(const uint4*)(Ah + ga2);
        *(uint4*)&AsL[(r0 + 64) * 40 + s * 8] = *(const uint4*)(Al + ga2);
        size_t gb = (size_t)(n0 + r0) * 512 + k0 + s * 8;
        *(uint4*)&BsH[r0 * 40 + s * 8] = *(const uint4*)(BTh + gb);
        *(uint4*)&BsL[r0 * 40 + s * 8] = *(const uint4*)(BTl + gb);
        size_t gb2 = (size_t)(n0 + r0 + 64) * 512 + k0 + s * 8;
        *(uint4*)&BsH[(r0 + 64) * 40 + s * 8] = *(const uint4*)(BTh + gb2);
        *(uint4*)&BsL[(r0 + 64) * 40 + s * 8] = *(const uint4*)(BTl + gb2);
        __syncthreads();

        bf16x8 ah[4], al[4], bh[4], bl[4];
        #pragma unroll
        for (int i = 0; i < 4; ++i) {
            int row = wm + i * 16 + lr;
            ah[i] = *(const bf16x8*)&AsH[row * 40 + lg * 8];
            al[i] = *(const bf16x8*)&AsL[row * 40 + lg * 8];
        }
        #pragma unroll
        for (int j = 0; j < 4; ++j) {
            int row = wn + j * 16 + lr;
            bh[j] = *(const bf16x8*)&BsH[row * 40 + lg * 8];
            bl[j] = *(const bf16x8*)&BsL[row * 40 + lg * 8];
        }
        #pragma unroll
        for (int i = 0; i < 4; ++i)
            #pragma unroll
            for (int j = 0; j < 4; ++j) {
                acc[i][j] = __builtin_amdgcn_mfma_f32_16x16x32_bf16(ah[i], bh[j], acc[i][j], 0, 0, 0);
                acc[i][j] = __builtin_amdgcn_mfma_f32_16x16x32_bf16(ah[i], bl[j], acc[i][j], 0, 0, 0);
                acc[i][j] = __builtin_amdgcn_mfma_f32_16x16x32_bf16(al[i], bh[j], acc[i][j], 0, 0, 0);
            }
    }

    #pragma unroll
    for (int i = 0; i < 4; ++i)
        #pragma unroll
        for (int j = 0; j < 4; ++j) {
            int col = n0 + wn + j * 16 + lr;
            float bs = bias[col];
            #pragma unroll
            for (int r = 0; r < 4; ++r) {
                int row = m0 + wm + i * 16 + lg * 4 + r;
                float v = acc[i][j][r] + bs;
                size_t idx = (size_t)row * N + col;
                if (MODE == 0) {
                    C[idx] = v;
                } else if (MODE == 1) {
                    float g = G[(size_t)row * gstride + col];
                    C[idx] += v / (1.0f + __expf(-g));
                } else {
                    if (col < scaleCols) v *= 0.125f;
                    u16 hv = f2bf(v);
                    Ch[idx] = hv;
                    Cl[idx] = f2bf(v - bf2f(hv));
                }
            }
        }
}

// ------- transpose local V planes: qkv cols 1024..1535 -> VT[b][dim][seq] -------
__global__ __launch_bounds__(256)
void transpV(const u16* __restrict__ qh, const u16* __restrict__ ql,
             u16* __restrict__ VTh, u16* __restrict__ VTl)
{
    __shared__ u16 th[64 * 72], tl[64 * 72];
    const int s0 = blockIdx.x * 64, d0 = blockIdx.y * 64, b = blockIdx.z;
    const int tid = threadIdx.x;
    const int r = tid >> 2, c16 = (tid & 3) * 16;
    size_t src = (size_t)(b * SEQ + s0 + r) * 1536 + 1024 + d0 + c16;
    *(uint4*)&th[r * 72 + c16]     = *(const uint4*)(qh + src);
    *(uint4*)&th[r * 72 + c16 + 8] = *(const uint4*)(qh + src + 8);
    *(uint4*)&tl[r * 72 + c16]     = *(const uint4*)(ql + src);
    *(uint4*)&tl[r * 72 + c16 + 8] = *(const uint4*)(ql + src + 8);
    __syncthreads();
    u16 oh16[16], ol16[16];
    #pragma unroll
    for (int j = 0; j < 16; ++j) {
        oh16[j] = th[(c16 + j) * 72 + r];
        ol16[j] = tl[(c16 + j) * 72 + r];
    }
    size_t dst = (size_t)(b * 512 + d0 + r) * 2048 + s0 + c16;
    *(uint4*)(VTh + dst)     = ((uint4*)oh16)[0];
    *(uint4*)(VTh + dst + 8) = ((uint4*)oh16)[1];
    *(uint4*)(VTl + dst)     = ((uint4*)ol16)[0];
    *(uint4*)(VTl + dst + 8) = ((uint4*)ol16)[1];
}

// ------- pool xkv cols 0..1023 -> kc planes [384][512], vcT planes [b*512+d][192] -------
__global__ __launch_bounds__(256)
void pool_kv(const float* __restrict__ xkv, u16* __restrict__ kch, u16* __restrict__ kcl,
             u16* __restrict__ vcTh, u16* __restrict__ vcTl)
{
    int row = blockIdx.x;              // 0..383
    int b = row / NPOOLS, p = row % NPOOLS;
    const float* src = xkv + ((size_t)b * SEQ + (size_t)p * RATIO) * 2048;
    for (int d = threadIdx.x; d < 1024; d += 256) {
        float sv = 0.f;
        #pragma unroll
        for (int r = 0; r < RATIO; ++r) sv += src[(size_t)r * 2048 + d];
        sv *= 0.125f;
        u16 hv = f2bf(sv), lv = f2bf(sv - bf2f(hv));
        if (d < 512) {
            kch[(size_t)row * DM + d] = hv;
            kcl[(size_t)row * DM + d] = lv;
        } else {
            size_t o = (size_t)(b * 512 + (d - 512)) * NPOOLS + p;
            vcTh[o] = hv;
            vcTl[o] = lv;
        }
    }
}

// ------- gather xkv cols 1024..2047 at tidx -> kt planes [128][512], vtT [b*512+d][64] -------
__global__ __launch_bounds__(256)
void gather_kv(const float* __restrict__ xkv, const int* __restrict__ tidx,
               u16* __restrict__ kth, u16* __restrict__ ktl,
               u16* __restrict__ vtTh, u16* __restrict__ vtTl)
{
    int j = blockIdx.x;                // 0..127
    int b = j >> 6, jj = j & 63;
    int t = tidx[j];
    const float* src = xkv + ((size_t)b * SEQ + t) * 2048 + 1024;
    for (int d = threadIdx.x; d < 512; d += 256) {
        float kv = src[d];
        u16 hv = f2bf(kv);
        kth[(size_t)j * DM + d] = hv;
        ktl[(size_t)j * DM + d] = f2bf(kv - bf2f(hv));
        float vv = src[512 + d];
        u16 hv2 = f2bf(vv);
        size_t o = (size_t)(b * 512 + d) * TOPKN + jj;
        vtTh[o] = hv2;
        vtTl[o] = f2bf(vv - bf2f(hv2));
    }
}

// ---------------- importance GEMV ----------------
__global__ __launch_bounds__(256)
void gemv_imp(const float* __restrict__ x, const float* __restrict__ w,
              const float* __restrict__ bsc, float* __restrict__ imp)
{
    int row = blockIdx.x * 4 + (threadIdx.x >> 6);
    int lane = threadIdx.x & 63;
    const float* xr = x + (size_t)row * DM;
    float sv = 0.f;
    #pragma unroll
    for (int i = 0; i < 8; ++i) sv += xr[lane + i * 64] * w[lane + i * 64];
    #pragma unroll
    for (int off = 32; off; off >>= 1) sv += __shfl_xor(sv, off);
    if (lane == 0) imp[row] = sv + bsc[0];
}

// ---------------- top-64 per batch via full bitonic sort ----------------
__global__ __launch_bounds__(1024)
void topk_bitonic(const float* __restrict__ imp, int* __restrict__ tidx)
{
    __shared__ float v[SEQ];
    __shared__ int ix[SEQ];
    const int b = blockIdx.x, tid = threadIdx.x;
    for (int i = tid; i < SEQ; i += 1024) { v[i] = imp[(size_t)b * SEQ + i]; ix[i] = i; }
    __syncthreads();
    for (int k = 2; k <= SEQ; k <<= 1) {
        for (int j = k >> 1; j > 0; j >>= 1) {
            for (int i = tid; i < SEQ; i += 1024) {
                int l = i ^ j;
                if (l > i) {
                    float vi = v[i], vl = v[l];
                    int ii = ix[i], il = ix[l];
                    bool iAfterL = (vi < vl) || (vi == vl && ii > il);
                    if (((i & k) == 0) == iAfterL) {
                        v[i] = vl; v[l] = vi; ix[i] = il; ix[l] = ii;
                    }
                }
            }
            __syncthreads();
        }
    }
    if (tid < TOPKN) tidx[b * TOPKN + tid] = ix[tid];
}

// =====================================================================
// Merged attention (MFMA flash). All operands pre-converted bf16 planes:
// staging = pure uint4 copies; Q frags loaded directly (0.125 pre-folded).
// grid (32 qb, 8 h, 6 = branch*2 + b).
// =====================================================================
template<int BRANCH>
__device__ __forceinline__ void attn_body(
    u16* sKh, u16* sKl, u16* sVh, u16* sVl,
    const u16* __restrict__ Qh_g, const u16* __restrict__ Ql_g, int QS, int qoff,
    const u16* __restrict__ Kh_g, const u16* __restrict__ Kl_g, int KS, int koff, size_t krow0,
    const u16* __restrict__ Vh_g, const u16* __restrict__ Vl_g, int VS, size_t vrow0,
    const int* __restrict__ tix, u16* __restrict__ oh, u16* __restrict__ ol,
    int qb, int b)
{
    const int tid = threadIdx.x;
    const int w = tid >> 6, lane = tid & 63;
    const int lr = lane & 15, lg = lane >> 4;
    const int qrow0 = qb * 64 + w * 16;

    // Q fragments straight from planes
    bf16x8 Qh[2], Ql[2];
    {
        size_t qr = (size_t)(b * SEQ + qrow0 + lr) * QS + qoff;
        Qh[0] = *(const bf16x8*)(Qh_g + qr + lg * 8);
        Qh[1] = *(const bf16x8*)(Qh_g + qr + 32 + lg * 8);
        Ql[0] = *(const bf16x8*)(Ql_g + qr + lg * 8);
        Ql[1] = *(const bf16x8*)(Ql_g + qr + 32 + lg * 8);
    }

    int tj[4]; int tmin = 0x7fffffff;
    if (BRANCH == 2) {
        #pragma unroll
        for (int nf = 0; nf < 4; ++nf) {
            tj[nf] = tix[b * TOPKN + nf * 16 + lr];
            tmin = imini(tmin, tj[nf]);
        }
        tmin = imini(tmin, __shfl_xor(tmin, 1));
        tmin = imini(tmin, __shfl_xor(tmin, 2));
        tmin = imini(tmin, __shfl_xor(tmin, 4));
        tmin = imini(tmin, __shfl_xor(tmin, 8));
    }

    int t0 = 0, t1 = 0;
    if (BRANCH == 0) { t0 = imaxi(0, qb - 8); t1 = qb; }
    else if (BRANCH == 1) { t0 = 0; t1 = (qb == 0) ? 2 : imini(2, (qb * 8 + 6) >> 6); }

    f32x4 onf[4];
    #pragma unroll
    for (int i = 0; i < 4; ++i) onf[i] = (f32x4){0.f, 0.f, 0.f, 0.f};
    f32x4 lvec = (f32x4){0.f, 0.f, 0.f, 0.f};

    const int r_ = tid >> 2, c4 = tid & 3;          // K staging
    const int dd = tid >> 2, k4 = (tid & 3) * 16;   // V staging

    for (int t = t0; t <= t1; ++t) {
        const int kb = t * 64;
        __syncthreads();

        {   // K tile: rows=key, cols=dim (pure copies)
            size_t krow = krow0 + ((BRANCH == 2) ? r_ : (kb + r_));
            const u16* kh = Kh_g + krow * KS + koff + c4 * 16;
            const u16* kl = Kl_g + krow * KS + koff + c4 * 16;
            *(uint4*)&sKh[r_ * 72 + c4 * 16]     = *(const uint4*)(kh);
            *(uint4*)&sKh[r_ * 72 + c4 * 16 + 8] = *(const uint4*)(kh + 8);
            *(uint4*)&sKl[r_ * 72 + c4 * 16]     = *(const uint4*)(kl);
            *(uint4*)&sKl[r_ * 72 + c4 * 16 + 8] = *(const uint4*)(kl + 8);
        }
        {   // V tile (pre-transposed): rows=dim, cols=key (pure copies)
            size_t vrow = (vrow0 + dd) * VS + ((BRANCH == 2) ? 0 : kb) + k4;
            const u16* vh = Vh_g + vrow;
            const u16* vl = Vl_g + vrow;
            *(uint4*)&sVh[dd * 72 + k4]     = *(const uint4*)(vh);
            *(uint4*)&sVh[dd * 72 + k4 + 8] = *(const uint4*)(vh + 8);
            *(uint4*)&sVl[dd * 72 + k4]     = *(const uint4*)(vl);
            *(uint4*)&sVl[dd * 72 + k4 + 8] = *(const uint4*)(vl + 8);
        }
        __syncthreads();

        // S = Q @ K^T (3-plane split)
        f32x4 sf[4];
        #pragma unroll
        for (int nf = 0; nf < 4; ++nf) {
            sf[nf] = (f32x4){0.f, 0.f, 0.f, 0.f};
            #pragma unroll
            for (int ks = 0; ks < 2; ++ks) {
                bf16x8 bh = *(const bf16x8*)&sKh[(nf * 16 + lr) * 72 + ks * 32 + lg * 8];
                bf16x8 bl = *(const bf16x8*)&sKl[(nf * 16 + lr) * 72 + ks * 32 + lg * 8];
                sf[nf] = __builtin_amdgcn_mfma_f32_16x16x32_bf16(Qh[ks], bh, sf[nf], 0, 0, 0);
                sf[nf] = __builtin_amdgcn_mfma_f32_16x16x32_bf16(Qh[ks], bl, sf[nf], 0, 0, 0);
                sf[nf] = __builtin_amdgcn_mfma_f32_16x16x32_bf16(Ql[ks], bh, sf[nf], 0, 0, 0);
            }
        }
        __syncthreads();   // all waves done reading K -> P may alias it

        // mask + exp + write P planes (aliases K buffer, wave-private slice)
        u16* Ph = sKh + w * 1152;
        u16* Pl = sKl + w * 1152;
        #pragma unroll
        for (int nf = 0; nf < 4; ++nf) {
            #pragma unroll
            for (int rr = 0; rr < 4; ++rr) {
                int rq = qrow0 + lg * 4 + rr;
                int ck = kb + nf * 16 + lr;
                float s = sf[nf][rr];
                float p;
                if (BRANCH == 0) {
                    bool valid = (ck <= rq) && (rq - ck < WIN);
                    p = valid ? __expf(s) : 0.f;
                } else if (BRANCH == 1) {
                    bool valid = rq >= (ck + 1) * RATIO;
                    p = (rq < RATIO) ? 1.f : (valid ? __expf(s) : 0.f);
                } else {
                    bool valid = rq >= tj[nf];
                    p = (rq < tmin) ? 1.f : (valid ? __expf(s) : 0.f);
                }
                lvec[rr] += p;
                u16 ph_ = f2bf(p);
                Ph[(lg * 4 + rr) * 72 + nf * 16 + lr] = ph_;
                Pl[(lg * 4 + rr) * 72 + nf * 16 + lr] = f2bf(p - bf2f(ph_));
            }
        }

        // O += P @ V
        bf16x8 pah[2], pal[2];
        #pragma unroll
        for (int ks2 = 0; ks2 < 2; ++ks2) {
            pah[ks2] = *(const bf16x8*)&Ph[lr * 72 + ks2 * 32 + lg * 8];
            pal[ks2] = *(const bf16x8*)&Pl[lr * 72 + ks2 * 32 + lg * 8];
        }
        #pragma unroll
        for (int nd = 0; nd < 4; ++nd) {
            #pragma unroll
            for (int ks2 = 0; ks2 < 2; ++ks2) {
                bf16x8 vh = *(const bf16x8*)&sVh[(nd * 16 + lr) * 72 + ks2 * 32 + lg * 8];
                bf16x8 vl = *(const bf16x8*)&sVl[(nd * 16 + lr) * 72 + ks2 * 32 + lg * 8];
                onf[nd] = __builtin_amdgcn_mfma_f32_16x16x32_bf16(pah[ks2], vh, onf[nd], 0, 0, 0);
                onf[nd] = __builtin_amdgcn_mfma_f32_16x16x32_bf16(pah[ks2], vl, onf[nd], 0, 0, 0);
                onf[nd] = __builtin_amdgcn_mfma_f32_16x16x32_bf16(pal[ks2], vh, onf[nd], 0, 0, 0);
            }
        }
    }

    #pragma unroll
    for (int bit = 1; bit <= 8; bit <<= 1) {
        lvec[0] += __shfl_xor(lvec[0], bit);
        lvec[1] += __shfl_xor(lvec[1], bit);
        lvec[2] += __shfl_xor(lvec[2], bit);
        lvec[3] += __shfl_xor(lvec[3], bit);
    }
    f32x4 inv;
    #pragma unroll
    for (int rr = 0; rr < 4; ++rr) inv[rr] = 1.0f / lvec[rr];

    const int h = blockIdx.y;
    #pragma unroll
    for (int nd = 0; nd < 4; ++nd) {
        #pragma unroll
        for (int rr = 0; rr < 4; ++rr) {
            int row = b * SEQ + qrow0 + lg * 4 + rr;
            size_t idx = (size_t)row * DM + h * HDIM + nd * 16 + lr;
            float v = onf[nd][rr] * inv[rr];
            u16 hv = f2bf(v);
            oh[idx] = hv;
            ol[idx] = f2bf(v - bf2f(hv));
        }
    }
}

__global__ __launch_bounds__(256)
void attn_all(const u16* __restrict__ qkvh, const u16* __restrict__ qkvl,
              const u16* __restrict__ VTlh, const u16* __restrict__ VTll,
              const u16* __restrict__ fqqh, const u16* __restrict__ fqql,
              const u16* __restrict__ kch, const u16* __restrict__ kcl,
              const u16* __restrict__ vcTh, const u16* __restrict__ vcTl,
              const u16* __restrict__ kth, const u16* __restrict__ ktl,
              const u16* __restrict__ vtTh, const u16* __restrict__ vtTl,
              const int* __restrict__ tidx,
              u16* __restrict__ aLh, u16* __restrict__ aLl,
              u16* __restrict__ aCh, u16* __restrict__ aCl,
              u16* __restrict__ aTh, u16* __restrict__ aTl)
{
    __shared__ __align__(16) u16 sKh[64 * 72], sKl[64 * 72], sVh[64 * 72], sVl[64 * 72];
    const int qb = blockIdx.x, h = blockIdx.y;
    const int branch = blockIdx.z >> 1, b = blockIdx.z & 1;
    const size_t vrow0 = (size_t)(b * 512 + h * HDIM);
    if (branch == 0) {
        attn_body<0>(sKh, sKl, sVh, sVl,
                     qkvh, qkvl, 1536, h * HDIM,
                     qkvh, qkvl, 1536, 512 + h * HDIM, (size_t)b * SEQ,
                     VTlh, VTll, 2048, vrow0,
                     nullptr, aLh, aLl, qb, b);
    } else if (branch == 1) {
        attn_body<1>(sKh, sKl, sVh, sVl,
                     fqqh, fqql, 1024, h * HDIM,
                     kch, kcl, 512, h * HDIM, (size_t)b * NPOOLS,
                     vcTh, vcTl, NPOOLS, vrow0,
                     nullptr, aCh, aCl, qb, b);
    } else {
        attn_body<2>(sKh, sKl, sVh, sVl,
                     fqqh, fqql, 1024, 512 + h * HDIM,
                     kth, ktl, 512, h * HDIM, (size_t)b * TOPKN,
                     vtTh, vtTl, TOPKN, vrow0,
                     tidx, aTh, aTl, qb, b);
    }
}

extern "C" void kernel_launch(void* const* d_in, const int* in_sizes, int n_in,
                              void* d_out, int out_size, void* d_ws, size_t ws_size,
                              hipStream_t stream)
{
    const float* x      = (const float*)d_in[0];
    const float* lqkv_W = (const float*)d_in[1];
    const float* lqkv_b = (const float*)d_in[2];
    const float* lout_W = (const float*)d_in[3];
    const float* lout_b = (const float*)d_in[4];
    const float* cq_W   = (const float*)d_in[5];
    const float* cq_b   = (const float*)d_in[6];
    const float* ck_W   = (const float*)d_in[7];
    const float* ck_b   = (const float*)d_in[8];
    const float* cv_W   = (const float*)d_in[9];
    const float* cv_b   = (const float*)d_in[10];
    const float* cout_W = (const float*)d_in[11];
    const float* cout_b = (const float*)d_in[12];
    const float* gc_W   = (const float*)d_in[13];
    const float* gc_b   = (const float*)d_in[14];
    const float* imp_W  = (const float*)d_in[15];
    const float* imp_b  = (const float*)d_in[16];
    const float* tq_W   = (const float*)d_in[17];
    const float* tq_b   = (const float*)d_in[18];
    const float* tk_W   = (const float*)d_in[19];
    const float* tk_b   = (const float*)d_in[20];
    const float* tv_W   = (const float*)d_in[21];
    const float* tv_b   = (const float*)d_in[22];
    const float* tout_W = (const float*)d_in[23];
    const float* tout_b = (const float*)d_in[24];
    const float* gt_W   = (const float*)d_in[25];
    const float* gt_b   = (const float*)d_in[26];
    float* out = (float*)d_out;

    char* wsb = (char*)d_ws;
    size_t off = 0;
    auto carve = [&](size_t bytes) { void* p = wsb + off; off += (bytes + 255) & ~(size_t)255; return p; };
    u16*   qkvh  = (u16*)  carve(4096ull * 1536 * 2);   // q(x0.125)|k|v planes
    u16*   qkvl  = (u16*)  carve(4096ull * 1536 * 2);
    u16*   fqqh  = (u16*)  carve(4096ull * 1024 * 2);   // qc|qt planes (x0.125)
    u16*   fqql  = (u16*)  carve(4096ull * 1024 * 2);
    float* gates = (float*)carve(4096ull * 1024 * 4);   // gC|gT fp32
    // region X: xkv fp32 aliased by the 6 attention-output planes (disjoint lifetimes)
    char*  X     = (char*) carve(4096ull * 2048 * 4);
    float* xkv   = (float*)X;
    u16*   aLh   = (u16*)(X);
    u16*   aLl   = (u16*)(X + 1 * 4194304);
    u16*   aCh   = (u16*)(X + 2 * 4194304);
    u16*   aCl   = (u16*)(X + 3 * 4194304);
    u16*   aTh   = (u16*)(X + 4 * 4194304);
    u16*   aTl   = (u16*)(X + 5 * 4194304);
    u16*   VTlh  = (u16*)  carve(2ull * 512 * 2048 * 2);  // local V transposed planes
    u16*   VTll  = (u16*)  carve(2ull * 512 * 2048 * 2);
    u16*   xh    = (u16*)  carve(4096ull * 512 * 2);
    u16*   xl    = (u16*)  carve(4096ull * 512 * 2);
    u16*   WqkvTh= (u16*)  carve(1536ull * 512 * 2);
    u16*   WqkvTl= (u16*)  carve(1536ull * 512 * 2);
    u16*   Wq2Th = (u16*)  carve(1024ull * 512 * 2);
    u16*   Wq2Tl = (u16*)  carve(1024ull * 512 * 2);
    u16*   Wg2Th = (u16*)  carve(1024ull * 512 * 2);
    u16*   Wg2Tl = (u16*)  carve(1024ull * 512 * 2);
    u16*   WkvTh = (u16*)  carve(2048ull * 512 * 2);
    u16*   WkvTl = (u16*)  carve(2048ull * 512 * 2);
    u16*   WLoTh = (u16*)  carve(512ull * 512 * 2);
    u16*   WLoTl = (u16*)  carve(512ull * 512 * 2);
    u16*   WCoTh = (u16*)  carve(512ull * 512 * 2);
    u16*   WCoTl = (u16*)  carve(512ull * 512 * 2);
    u16*   WToTh = (u16*)  carve(512ull * 512 * 2);
    u16*   WToTl = (u16*)  carve(512ull * 512 * 2);
    float* bq2   = (float*)carve(1024ull * 4);
    float* bg2   = (float*)carve(1024ull * 4);
    float* bkv   = (float*)carve(2048ull * 4);
    u16*   kch   = (u16*)  carve(384ull * 512 * 2);
    u16*   kcl   = (u16*)  carve(384ull * 512 * 2);
    u16*   vcTh  = (u16*)  carve(2ull * 512 * 192 * 2);
    u16*   vcTl  = (u16*)  carve(2ull * 512 * 192 * 2);
    u16*   kth   = (u16*)  carve(128ull * 512 * 2);
    u16*   ktl   = (u16*)  carve(128ull * 512 * 2);
    u16*   vtTh  = (u16*)  carve(2ull * 512 * 64 * 2);
    u16*   vtTl  = (u16*)  carve(2ull * 512 * 64 * 2);
    float* impb  = (float*)carve(4096ull * 4);
    int*   tidx  = (int*)  carve(128ull * 4);

    // ---- conversions ----
    conv_act<<<1024, 256, 0, stream>>>(x, xh, xl, 4096 * 512 / 8);
    conv_wT<<<dim3(24, 8), 256, 0, stream>>>(lqkv_W, 1536, WqkvTh, WqkvTl, 0);
    conv_wT11<<<dim3(8, 8, 11), 256, 0, stream>>>(cq_W, tq_W, gc_W, gt_W, lout_W, cout_W, tout_W,
                                                  ck_W, cv_W, tk_W, tv_W,
                                                  Wq2Th, Wq2Tl, Wg2Th, Wg2Tl,
                                                  WLoTh, WLoTl, WCoTh, WCoTl, WToTh, WToTl,
                                                  WkvTh, WkvTl);
    bcat_all<<<16, 256, 0, stream>>>(cq_b, tq_b, gc_b, gt_b, ck_b, cv_b, tk_b, tv_b, bq2, bg2, bkv);

    // ---- projections ----
    gemm_mfma<2><<<dim3(12, 32), 256, 0, stream>>>(xh, xl, WqkvTh, WqkvTl, lqkv_b,
                                                   nullptr, qkvh, qkvl, nullptr, 0, 1536, 512);
    transpV<<<dim3(32, 8, 2), 256, 0, stream>>>(qkvh, qkvl, VTlh, VTll);
    gemm_mfma<0><<<dim3(16, 32), 256, 0, stream>>>(xh, xl, WkvTh, WkvTl, bkv,
                                                   xkv, nullptr, nullptr, nullptr, 0, 2048, 0);
    gemv_imp<<<1024, 256, 0, stream>>>(x, imp_W, imp_b, impb);
    topk_bitonic<<<2, 1024, 0, stream>>>(impb, tidx);
    pool_kv<<<384, 256, 0, stream>>>(xkv, kch, kcl, vcTh, vcTl);
    gather_kv<<<128, 256, 0, stream>>>(xkv, tidx, kth, ktl, vtTh, vtTl);
    gemm_mfma<2><<<dim3(8, 32), 256, 0, stream>>>(xh, xl, Wq2Th, Wq2Tl, bq2,
                                                  nullptr, fqqh, fqql, nullptr, 0, 1024, 1024);
    gemm_mfma<0><<<dim3(8, 32), 256, 0, stream>>>(xh, xl, Wg2Th, Wg2Tl, bg2,
                                                  gates, nullptr, nullptr, nullptr, 0, 1024, 0);

    // ---- merged attention (writes a* planes into region X) ----
    attn_all<<<dim3(32, 8, 6), 256, 0, stream>>>(qkvh, qkvl, VTlh, VTll, fqqh, fqql,
                                                 kch, kcl, vcTh, vcTl, kth, ktl, vtTh, vtTl,
                                                 tidx, aLh, aLl, aCh, aCl, aTh, aTl);

    // ---- output projections: out = projL + sig(gC)*projC + sig(gT)*projT ----
    gemm_mfma<0><<<dim3(4, 32), 256, 0, stream>>>(aLh, aLl, WLoTh, WLoTl, lout_b,
                                                  out, nullptr, nullptr, nullptr, 0, 512, 0);
    gemm_mfma<1><<<dim3(4, 32), 256, 0, stream>>>(aCh, aCl, WCoTh, WCoTl, cout_b,
                                                  out, nullptr, nullptr, gates, 1024, 512, 0);
    gemm_mfma<1><<<dim3(4, 32), 256, 0, stream>>>(aTh, aTl, WToTh, WToTl, tout_b,
                                                  out, nullptr, nullptr, gates + 512, 1024, 512, 0);
}

// Round 13
// 407.736 us; speedup vs baseline: 1.0635x; 1.0635x over previous
//
#include <hip/hip_runtime.h>
#include <cstdint>
#include <cstddef>

#define HNUM 8
#define HDIM 64
#define WIN 512
#define RATIO 8
#define TOPKN 64
#define BATCH 2
#define SEQ 2048
#define DM 512
#define NPOOLS 192

typedef unsigned short u16;
typedef __attribute__((ext_vector_type(8))) short bf16x8;
typedef __attribute__((ext_vector_type(4))) float f32x4;

static __device__ __forceinline__ int imaxi(int a, int b){ return a > b ? a : b; }
static __device__ __forceinline__ int imini(int a, int b){ return a < b ? a : b; }

static __device__ __forceinline__ u16 f2bf(float v) {
    union { float f; uint32_t u; } c; c.f = v;
    uint32_t r = c.u + 0x7fffu + ((c.u >> 16) & 1u);
    return (u16)(r >> 16);
}
static __device__ __forceinline__ float bf2f(u16 u) {
    union { uint32_t u; float f; } c; c.u = ((uint32_t)u) << 16;
    return c.f;
}

// ---------------- fp32 -> (hi, lo) bf16 planes, elementwise ----------------
__global__ __launch_bounds__(256)
void conv_act(const float* __restrict__ in, u16* __restrict__ h, u16* __restrict__ l, int n8)
{
    int i = blockIdx.x * 256 + threadIdx.x;
    if (i >= n8) return;
    const float4* p = (const float4*)(in + (size_t)i * 8);
    float4 a = p[0], b = p[1];
    float v[8] = {a.x, a.y, a.z, a.w, b.x, b.y, b.z, b.w};
    u16 hs[8], ls[8];
    #pragma unroll
    for (int j = 0; j < 8; ++j) {
        hs[j] = f2bf(v[j]);
        ls[j] = f2bf(v[j] - bf2f(hs[j]));
    }
    *(uint4*)(h + (size_t)i * 8) = *(uint4*)hs;
    *(uint4*)(l + (size_t)i * 8) = *(uint4*)ls;
}

// ------------- weight transpose-convert: W[512][N] -> WT planes [N][512] -------------
__global__ __launch_bounds__(256)
void conv_wT(const float* __restrict__ W, int N,
             u16* __restrict__ WTh, u16* __restrict__ WTl, int dstRowOff)
{
    __shared__ float t[64][65];
    const int n0 = blockIdx.x * 64, k0 = blockIdx.y * 64;
    const int tid = threadIdx.x;
    const int tk = tid >> 4, tn = (tid & 15) * 4;
    #pragma unroll
    for (int r = 0; r < 4; ++r) {
        int k = tk + r * 16;
        float4 v = *(const float4*)(W + (size_t)(k0 + k) * N + n0 + tn);
        t[k][tn + 0] = v.x; t[k][tn + 1] = v.y; t[k][tn + 2] = v.z; t[k][tn + 3] = v.w;
    }
    __syncthreads();
    const int nl = tid >> 2, s = tid & 3;
    u16 hs[16], ls[16];
    #pragma unroll
    for (int j = 0; j < 16; ++j) {
        float v = t[s * 16 + j][nl];
        hs[j] = f2bf(v);
        ls[j] = f2bf(v - bf2f(hs[j]));
    }
    size_t base = (size_t)(dstRowOff + n0 + nl) * 512 + k0 + s * 16;
    *(uint4*)(WTh + base)     = ((uint4*)hs)[0];
    *(uint4*)(WTh + base + 8) = ((uint4*)hs)[1];
    *(uint4*)(WTl + base)     = ((uint4*)ls)[0];
    *(uint4*)(WTl + base + 8) = ((uint4*)ls)[1];
}

// ------------- 11x (512x512) weight transpose-convert in one launch -------------
// z0-7: cq,tq,gc,gt,ck,cv,tk,tv -> WmegaT rows 1536+z*512 ; z8-10: lout,cout,tout
__global__ __launch_bounds__(256)
void conv_wT11(const float* __restrict__ w0, const float* __restrict__ w1,
               const float* __restrict__ w2, const float* __restrict__ w3,
               const float* __restrict__ w4, const float* __restrict__ w5,
               const float* __restrict__ w6, const float* __restrict__ w7,
               const float* __restrict__ w8, const float* __restrict__ w9,
               const float* __restrict__ w10,
               u16* __restrict__ WmegaTh, u16* __restrict__ WmegaTl,
               u16* __restrict__ WLoTh, u16* __restrict__ WLoTl,
               u16* __restrict__ WCoTh, u16* __restrict__ WCoTl,
               u16* __restrict__ WToTh, u16* __restrict__ WToTl)
{
    const float* W; u16* dh; u16* dl; int rowoff = 0;
    switch (blockIdx.z) {
        case 0:  W = w0;  dh = WmegaTh; dl = WmegaTl; rowoff = 1536; break;
        case 1:  W = w1;  dh = WmegaTh; dl = WmegaTl; rowoff = 2048; break;
        case 2:  W = w2;  dh = WmegaTh; dl = WmegaTl; rowoff = 2560; break;
        case 3:  W = w3;  dh = WmegaTh; dl = WmegaTl; rowoff = 3072; break;
        case 4:  W = w4;  dh = WmegaTh; dl = WmegaTl; rowoff = 3584; break;
        case 5:  W = w5;  dh = WmegaTh; dl = WmegaTl; rowoff = 4096; break;
        case 6:  W = w6;  dh = WmegaTh; dl = WmegaTl; rowoff = 4608; break;
        case 7:  W = w7;  dh = WmegaTh; dl = WmegaTl; rowoff = 5120; break;
        case 8:  W = w8;  dh = WLoTh;   dl = WLoTl;   rowoff = 0;    break;
        case 9:  W = w9;  dh = WCoTh;   dl = WCoTl;   rowoff = 0;    break;
        default: W = w10; dh = WToTh;   dl = WToTl;   rowoff = 0;    break;
    }
    __shared__ float t[64][65];
    const int n0 = blockIdx.x * 64, k0 = blockIdx.y * 64;
    const int tid = threadIdx.x;
    const int tk = tid >> 4, tn = (tid & 15) * 4;
    #pragma unroll
    for (int r = 0; r < 4; ++r) {
        int k = tk + r * 16;
        float4 v = *(const float4*)(W + (size_t)(k0 + k) * 512 + n0 + tn);
        t[k][tn + 0] = v.x; t[k][tn + 1] = v.y; t[k][tn + 2] = v.z; t[k][tn + 3] = v.w;
    }
    __syncthreads();
    const int nl = tid >> 2, s = tid & 3;
    u16 hs[16], ls[16];
    #pragma unroll
    for (int j = 0; j < 16; ++j) {
        float v = t[s * 16 + j][nl];
        hs[j] = f2bf(v);
        ls[j] = f2bf(v - bf2f(hs[j]));
    }
    size_t base = (size_t)(rowoff + n0 + nl) * 512 + k0 + s * 16;
    *(uint4*)(dh + base)     = ((uint4*)hs)[0];
    *(uint4*)(dh + base + 8) = ((uint4*)hs)[1];
    *(uint4*)(dl + base)     = ((uint4*)ls)[0];
    *(uint4*)(dl + base + 8) = ((uint4*)ls)[1];
}

// ---------------- mega bias concat [5632] ----------------
__global__ void bcat_mega(const float* __restrict__ lqkv_b,
                          const float* __restrict__ cq_b, const float* __restrict__ tq_b,
                          const float* __restrict__ gc_b, const float* __restrict__ gt_b,
                          const float* __restrict__ ck_b, const float* __restrict__ cv_b,
                          const float* __restrict__ tk_b, const float* __restrict__ tv_b,
                          float* __restrict__ bm)
{
    int i = blockIdx.x * 256 + threadIdx.x;
    if (i >= 5632) return;
    float v;
    if (i < 1536) v = lqkv_b[i];
    else if (i < 2048) v = cq_b[i - 1536];
    else if (i < 2560) v = tq_b[i - 2048];
    else if (i < 3072) v = gc_b[i - 2560];
    else if (i < 3584) v = gt_b[i - 3072];
    else if (i < 4096) v = ck_b[i - 3584];
    else if (i < 4608) v = cv_b[i - 4096];
    else if (i < 5120) v = tk_b[i - 4608];
    else v = tv_b[i - 5120];
    bm[i] = v;
}

// =====================================================================
// Mega-GEMM: A = x planes [4096][512], B = WmegaT [5632][512], one launch.
// Block-uniform epilogue ranges (n0 multiples of 128):
//   [0,1536)    -> qkv planes, x0.125 for col<512
//   [1536,2560) -> fqq planes (qc|qt), x0.125
//   [2560,3584) -> gates fp32
//   [3584,5632) -> xkv fp32
// =====================================================================
__global__ __launch_bounds__(256)
void gemm_mega(const u16* __restrict__ Ah, const u16* __restrict__ Al,
               const u16* __restrict__ BTh, const u16* __restrict__ BTl,
               const float* __restrict__ bias,
               u16* __restrict__ qkvh, u16* __restrict__ qkvl,
               u16* __restrict__ fqqh, u16* __restrict__ fqql,
               float* __restrict__ gates, float* __restrict__ xkv)
{
    __shared__ __align__(16) u16 AsH[128 * 40], AsL[128 * 40], BsH[128 * 40], BsL[128 * 40];
    const int tid = threadIdx.x;
    const int m0 = blockIdx.y * 128, n0 = blockIdx.x * 128;
    const int wid = tid >> 6, lane = tid & 63;
    const int wm = (wid >> 1) * 64, wn = (wid & 1) * 64;
    const int lr = lane & 15, lg = lane >> 4;

    f32x4 acc[4][4];
    #pragma unroll
    for (int i = 0; i < 4; ++i)
        #pragma unroll
        for (int j = 0; j < 4; ++j) acc[i][j] = (f32x4){0.f, 0.f, 0.f, 0.f};

    const int r0 = tid >> 2, s = tid & 3;

    for (int k0 = 0; k0 < 512; k0 += 32) {
        __syncthreads();
        size_t ga = (size_t)(m0 + r0) * 512 + k0 + s * 8;
        *(uint4*)&AsH[r0 * 40 + s * 8] = *(const uint4*)(Ah + ga);
        *(uint4*)&AsL[r0 * 40 + s * 8] = *(const uint4*)(Al + ga);
        size_t ga2 = (size_t)(m0 + r0 + 64) * 512 + k0 + s * 8;
        *(uint4*)&AsH[(r0 + 64) * 40 + s * 8] = *(const uint4*)(Ah + ga2);
        *(uint4*)&AsL[(r0 + 64) * 40 + s * 8] = *(const uint4*)(Al + ga2);
        size_t gb = (size_t)(n0 + r0) * 512 + k0 + s * 8;
        *(uint4*)&BsH[r0 * 40 + s * 8] = *(const uint4*)(BTh + gb);
        *(uint4*)&BsL[r0 * 40 + s * 8] = *(const uint4*)(BTl + gb);
        size_t gb2 = (size_t)(n0 + r0 + 64) * 512 + k0 + s * 8;
        *(uint4*)&BsH[(r0 + 64) * 40 + s * 8] = *(const uint4*)(BTh + gb2);
        *(uint4*)&BsL[(r0 + 64) * 40 + s * 8] = *(const uint4*)(BTl + gb2);
        __syncthreads();

        bf16x8 ah[4], al[4], bh[4], bl[4];
        #pragma unroll
        for (int i = 0; i < 4; ++i) {
            int row = wm + i * 16 + lr;
            ah[i] = *(const bf16x8*)&AsH[row * 40 + lg * 8];
            al[i] = *(const bf16x8*)&AsL[row * 40 + lg * 8];
        }
        #pragma unroll
        for (int j = 0; j < 4; ++j) {
            int row = wn + j * 16 + lr;
            bh[j] = *(const bf16x8*)&BsH[row * 40 + lg * 8];
            bl[j] = *(const bf16x8*)&BsL[row * 40 + lg * 8];
        }
        #pragma unroll
        for (int i = 0; i < 4; ++i)
            #pragma unroll
            for (int j = 0; j < 4; ++j) {
                acc[i][j] = __builtin_amdgcn_mfma_f32_16x16x32_bf16(ah[i], bh[j], acc[i][j], 0, 0, 0);
                acc[i][j] = __builtin_amdgcn_mfma_f32_16x16x32_bf16(ah[i], bl[j], acc[i][j], 0, 0, 0);
                acc[i][j] = __builtin_amdgcn_mfma_f32_16x16x32_bf16(al[i], bh[j], acc[i][j], 0, 0, 0);
            }
    }

    #pragma unroll
    for (int i = 0; i < 4; ++i)
        #pragma unroll
        for (int j = 0; j < 4; ++j) {
            int gcol = n0 + wn + j * 16 + lr;
            float bs = bias[gcol];
            #pragma unroll
            for (int r = 0; r < 4; ++r) {
                int row = m0 + wm + i * 16 + lg * 4 + r;
                float v = acc[i][j][r] + bs;
                if (n0 < 1536) {                 // qkv planes (q cols x0.125)
                    float vv = (gcol < 512) ? v * 0.125f : v;
                    size_t idx = (size_t)row * 1536 + gcol;
                    u16 hv = f2bf(vv);
                    qkvh[idx] = hv;
                    qkvl[idx] = f2bf(vv - bf2f(hv));
                } else if (n0 < 2560) {          // fqq planes x0.125
                    float vv = v * 0.125f;
                    size_t idx = (size_t)row * 1024 + (gcol - 1536);
                    u16 hv = f2bf(vv);
                    fqqh[idx] = hv;
                    fqql[idx] = f2bf(vv - bf2f(hv));
                } else if (n0 < 3584) {          // gates fp32
                    gates[(size_t)row * 1024 + (gcol - 2560)] = v;
                } else {                         // xkv fp32
                    xkv[(size_t)row * 2048 + (gcol - 3584)] = v;
                }
            }
        }
}

// ---------------- split-bf16 MFMA GEMM (out projections) ----------------
// MODE 0: C = A@B + bias   |   MODE 1: C += sigmoid(G) * (A@B + bias)
template<int MODE>
__global__ __launch_bounds__(256)
void gemm_mfma(const u16* __restrict__ Ah, const u16* __restrict__ Al,
               const u16* __restrict__ BTh, const u16* __restrict__ BTl,
               const float* __restrict__ bias, float* __restrict__ C,
               const float* __restrict__ G, int gstride, int N)
{
    __shared__ __align__(16) u16 AsH[128 * 40], AsL[128 * 40], BsH[128 * 40], BsL[128 * 40];
    const int tid = threadIdx.x;
    const int m0 = blockIdx.y * 128, n0 = blockIdx.x * 128;
    const int wid = tid >> 6, lane = tid & 63;
    const int wm = (wid >> 1) * 64, wn = (wid & 1) * 64;
    const int lr = lane & 15, lg = lane >> 4;

    f32x4 acc[4][4];
    #pragma unroll
    for (int i = 0; i < 4; ++i)
        #pragma unroll
        for (int j = 0; j < 4; ++j) acc[i][j] = (f32x4){0.f, 0.f, 0.f, 0.f};

    const int r0 = tid >> 2, s = tid & 3;

    for (int k0 = 0; k0 < 512; k0 += 32) {
        __syncthreads();
        size_t ga = (size_t)(m0 + r0) * 512 + k0 + s * 8;
        *(uint4*)&AsH[r0 * 40 + s * 8] = *(const uint4*)(Ah + ga);
        *(uint4*)&AsL[r0 * 40 + s * 8] = *(const uint4*)(Al + ga);
        size_t ga2 = (size_t)(m0 + r0 + 64) * 512 + k0 + s * 8;
        *(uint4*)&AsH[(r0 + 64) * 40 + s * 8] = *(const uint4*)(Ah + ga2);
        *(uint4*)&AsL[(r0 + 64) * 40 + s * 8] = *(const uint4*)(Al + ga2);
        size_t gb = (size_t)(n0 + r0) * 512 + k0 + s * 8;
        *(uint4*)&BsH[r0 * 40 + s * 8] = *(const uint4*)(BTh + gb);
        *(uint4*)&BsL[r0 * 40 + s * 8] = *(const uint4*)(BTl + gb);
        size_t gb2 = (size_t)(n0 + r0 + 64) * 512 + k0 + s * 8;
        *(uint4*)&BsH[(r0 + 64) * 40 + s * 8] = *(const uint4*)(BTh + gb2);
        *(uint4*)&BsL[(r0 + 64) * 40 + s * 8] = *(const uint4*)(BTl + gb2);
        __syncthreads();

        bf16x8 ah[4], al[4], bh[4], bl[4];
        #pragma unroll
        for (int i = 0; i < 4; ++i) {
            int row = wm + i * 16 + lr;
            ah[i] = *(const bf16x8*)&AsH[row * 40 + lg * 8];
            al[i] = *(const bf16x8*)&AsL[row * 40 + lg * 8];
        }
        #pragma unroll
        for (int j = 0; j < 4; ++j) {
            int row = wn + j * 16 + lr;
            bh[j] = *(const bf16x8*)&BsH[row * 40 + lg * 8];
            bl[j] = *(const bf16x8*)&BsL[row * 40 + lg * 8];
        }
        #pragma unroll
        for (int i = 0; i < 4; ++i)
            #pragma unroll
            for (int j = 0; j < 4; ++j) {
                acc[i][j] = __builtin_amdgcn_mfma_f32_16x16x32_bf16(ah[i], bh[j], acc[i][j], 0, 0, 0);
                acc[i][j] = __builtin_amdgcn_mfma_f32_16x16x32_bf16(ah[i], bl[j], acc[i][j], 0, 0, 0);
                acc[i][j] = __builtin_amdgcn_mfma_f32_16x16x32_bf16(al[i], bh[j], acc[i][j], 0, 0, 0);
            }
    }

    #pragma unroll
    for (int i = 0; i < 4; ++i)
        #pragma unroll
        for (int j = 0; j < 4; ++j) {
            int col = n0 + wn + j * 16 + lr;
            float bs = bias[col];
            #pragma unroll
            for (int r = 0; r < 4; ++r) {
                int row = m0 + wm + i * 16 + lg * 4 + r;
                float v = acc[i][j][r] + bs;
                size_t idx = (size_t)row * N + col;
                if (MODE == 0) {
                    C[idx] = v;
                } else {
                    float g = G[(size_t)row * gstride + col];
                    C[idx] += v / (1.0f + __expf(-g));
                }
            }
        }
}

// ------- transpose local V planes: qkv cols 1024..1535 -> VT[b][dim][seq] -------
__global__ __launch_bounds__(256)
void transpV(const u16* __restrict__ qh, const u16* __restrict__ ql,
             u16* __restrict__ VTh, u16* __restrict__ VTl)
{
    __shared__ u16 th[64 * 72], tl[64 * 72];
    const int s0 = blockIdx.x * 64, d0 = blockIdx.y * 64, b = blockIdx.z;
    const int tid = threadIdx.x;
    const int r = tid >> 2, c16 = (tid & 3) * 16;
    size_t src = (size_t)(b * SEQ + s0 + r) * 1536 + 1024 + d0 + c16;
    *(uint4*)&th[r * 72 + c16]     = *(const uint4*)(qh + src);
    *(uint4*)&th[r * 72 + c16 + 8] = *(const uint4*)(qh + src + 8);
    *(uint4*)&tl[r * 72 + c16]     = *(const uint4*)(ql + src);
    *(uint4*)&tl[r * 72 + c16 + 8] = *(const uint4*)(ql + src + 8);
    __syncthreads();
    u16 oh16[16], ol16[16];
    #pragma unroll
    for (int j = 0; j < 16; ++j) {
        oh16[j] = th[(c16 + j) * 72 + r];
        ol16[j] = tl[(c16 + j) * 72 + r];
    }
    size_t dst = (size_t)(b * 512 + d0 + r) * 2048 + s0 + c16;
    *(uint4*)(VTh + dst)     = ((uint4*)oh16)[0];
    *(uint4*)(VTh + dst + 8) = ((uint4*)oh16)[1];
    *(uint4*)(VTl + dst)     = ((uint4*)ol16)[0];
    *(uint4*)(VTl + dst + 8) = ((uint4*)ol16)[1];
}

// ------- pool xkv cols 0..1023 -> kc planes [384][512], vcT planes [b*512+d][192] -------
__global__ __launch_bounds__(256)
void pool_kv(const float* __restrict__ xkv, u16* __restrict__ kch, u16* __restrict__ kcl,
             u16* __restrict__ vcTh, u16* __restrict__ vcTl)
{
    int row = blockIdx.x;              // 0..383
    int b = row / NPOOLS, p = row % NPOOLS;
    const float* src = xkv + ((size_t)b * SEQ + (size_t)p * RATIO) * 2048;
    for (int d = threadIdx.x; d < 1024; d += 256) {
        float sv = 0.f;
        #pragma unroll
        for (int r = 0; r < RATIO; ++r) sv += src[(size_t)r * 2048 + d];
        sv *= 0.125f;
        u16 hv = f2bf(sv), lv = f2bf(sv - bf2f(hv));
        if (d < 512) {
            kch[(size_t)row * DM + d] = hv;
            kcl[(size_t)row * DM + d] = lv;
        } else {
            size_t o = (size_t)(b * 512 + (d - 512)) * NPOOLS + p;
            vcTh[o] = hv;
            vcTl[o] = lv;
        }
    }
}

// ------- gather xkv cols 1024..2047 at tidx -> kt planes [128][512], vtT [b*512+d][64] -------
__global__ __launch_bounds__(256)
void gather_kv(const float* __restrict__ xkv, const int* __restrict__ tidx,
               u16* __restrict__ kth, u16* __restrict__ ktl,
               u16* __restrict__ vtTh, u16* __restrict__ vtTl)
{
    int j = blockIdx.x;                // 0..127
    int b = j >> 6, jj = j & 63;
    int t = tidx[j];
    const float* src = xkv + ((size_t)b * SEQ + t) * 2048 + 1024;
    for (int d = threadIdx.x; d < 512; d += 256) {
        float kv = src[d];
        u16 hv = f2bf(kv);
        kth[(size_t)j * DM + d] = hv;
        ktl[(size_t)j * DM + d] = f2bf(kv - bf2f(hv));
        float vv = src[512 + d];
        u16 hv2 = f2bf(vv);
        size_t o = (size_t)(b * 512 + d) * TOPKN + jj;
        vtTh[o] = hv2;
        vtTl[o] = f2bf(vv - bf2f(hv2));
    }
}

// ---------------- importance GEMV ----------------
__global__ __launch_bounds__(256)
void gemv_imp(const float* __restrict__ x, const float* __restrict__ w,
              const float* __restrict__ bsc, float* __restrict__ imp)
{
    int row = blockIdx.x * 4 + (threadIdx.x >> 6);
    int lane = threadIdx.x & 63;
    const float* xr = x + (size_t)row * DM;
    float sv = 0.f;
    #pragma unroll
    for (int i = 0; i < 8; ++i) sv += xr[lane + i * 64] * w[lane + i * 64];
    #pragma unroll
    for (int off = 32; off; off >>= 1) sv += __shfl_xor(sv, off);
    if (lane == 0) imp[row] = sv + bsc[0];
}

// ---------------- top-64 per batch via full bitonic sort ----------------
__global__ __launch_bounds__(1024)
void topk_bitonic(const float* __restrict__ imp, int* __restrict__ tidx)
{
    __shared__ float v[SEQ];
    __shared__ int ix[SEQ];
    const int b = blockIdx.x, tid = threadIdx.x;
    for (int i = tid; i < SEQ; i += 1024) { v[i] = imp[(size_t)b * SEQ + i]; ix[i] = i; }
    __syncthreads();
    for (int k = 2; k <= SEQ; k <<= 1) {
        for (int j = k >> 1; j > 0; j >>= 1) {
            for (int i = tid; i < SEQ; i += 1024) {
                int l = i ^ j;
                if (l > i) {
                    float vi = v[i], vl = v[l];
                    int ii = ix[i], il = ix[l];
                    bool iAfterL = (vi < vl) || (vi == vl && ii > il);
                    if (((i & k) == 0) == iAfterL) {
                        v[i] = vl; v[l] = vi; ix[i] = il; ix[l] = ii;
                    }
                }
            }
            __syncthreads();
        }
    }
    if (tid < TOPKN) tidx[b * TOPKN + tid] = ix[tid];
}

// =====================================================================
// Merged attention (MFMA flash), bf16-plane operands, grid (32, 8, 6).
// =====================================================================
template<int BRANCH>
__device__ __forceinline__ void attn_body(
    u16* sKh, u16* sKl, u16* sVh, u16* sVl,
    const u16* __restrict__ Qh_g, const u16* __restrict__ Ql_g, int QS, int qoff,
    const u16* __restrict__ Kh_g, const u16* __restrict__ Kl_g, int KS, int koff, size_t krow0,
    const u16* __restrict__ Vh_g, const u16* __restrict__ Vl_g, int VS, size_t vrow0,
    const int* __restrict__ tix, u16* __restrict__ oh, u16* __restrict__ ol,
    int qb, int b)
{
    const int tid = threadIdx.x;
    const int w = tid >> 6, lane = tid & 63;
    const int lr = lane & 15, lg = lane >> 4;
    const int qrow0 = qb * 64 + w * 16;

    bf16x8 Qh[2], Ql[2];
    {
        size_t qr = (size_t)(b * SEQ + qrow0 + lr) * QS + qoff;
        Qh[0] = *(const bf16x8*)(Qh_g + qr + lg * 8);
        Qh[1] = *(const bf16x8*)(Qh_g + qr + 32 + lg * 8);
        Ql[0] = *(const bf16x8*)(Ql_g + qr + lg * 8);
        Ql[1] = *(const bf16x8*)(Ql_g + qr + 32 + lg * 8);
    }

    int tj[4]; int tmin = 0x7fffffff;
    if (BRANCH == 2) {
        #pragma unroll
        for (int nf = 0; nf < 4; ++nf) {
            tj[nf] = tix[b * TOPKN + nf * 16 + lr];
            tmin = imini(tmin, tj[nf]);
        }
        tmin = imini(tmin, __shfl_xor(tmin, 1));
        tmin = imini(tmin, __shfl_xor(tmin, 2));
        tmin = imini(tmin, __shfl_xor(tmin, 4));
        tmin = imini(tmin, __shfl_xor(tmin, 8));
    }

    int t0 = 0, t1 = 0;
    if (BRANCH == 0) { t0 = imaxi(0, qb - 8); t1 = qb; }
    else if (BRANCH == 1) { t0 = 0; t1 = (qb == 0) ? 2 : imini(2, (qb * 8 + 6) >> 6); }

    f32x4 onf[4];
    #pragma unroll
    for (int i = 0; i < 4; ++i) onf[i] = (f32x4){0.f, 0.f, 0.f, 0.f};
    f32x4 lvec = (f32x4){0.f, 0.f, 0.f, 0.f};

    const int r_ = tid >> 2, c4 = tid & 3;
    const int dd = tid >> 2, k4 = (tid & 3) * 16;

    for (int t = t0; t <= t1; ++t) {
        const int kb = t * 64;
        __syncthreads();

        {
            size_t krow = krow0 + ((BRANCH == 2) ? r_ : (kb + r_));
            const u16* kh = Kh_g + krow * KS + koff + c4 * 16;
            const u16* kl = Kl_g + krow * KS + koff + c4 * 16;
            *(uint4*)&sKh[r_ * 72 + c4 * 16]     = *(const uint4*)(kh);
            *(uint4*)&sKh[r_ * 72 + c4 * 16 + 8] = *(const uint4*)(kh + 8);
            *(uint4*)&sKl[r_ * 72 + c4 * 16]     = *(const uint4*)(kl);
            *(uint4*)&sKl[r_ * 72 + c4 * 16 + 8] = *(const uint4*)(kl + 8);
        }
        {
            size_t vrow = (vrow0 + dd) * VS + ((BRANCH == 2) ? 0 : kb) + k4;
            const u16* vh = Vh_g + vrow;
            const u16* vl = Vl_g + vrow;
            *(uint4*)&sVh[dd * 72 + k4]     = *(const uint4*)(vh);
            *(uint4*)&sVh[dd * 72 + k4 + 8] = *(const uint4*)(vh + 8);
            *(uint4*)&sVl[dd * 72 + k4]     = *(const uint4*)(vl);
            *(uint4*)&sVl[dd * 72 + k4 + 8] = *(const uint4*)(vl + 8);
        }
        __syncthreads();

        f32x4 sf[4];
        #pragma unroll
        for (int nf = 0; nf < 4; ++nf) {
            sf[nf] = (f32x4){0.f, 0.f, 0.f, 0.f};
            #pragma unroll
            for (int ks = 0; ks < 2; ++ks) {
                bf16x8 bh = *(const bf16x8*)&sKh[(nf * 16 + lr) * 72 + ks * 32 + lg * 8];
                bf16x8 bl = *(const bf16x8*)&sKl[(nf * 16 + lr) * 72 + ks * 32 + lg * 8];
                sf[nf] = __builtin_amdgcn_mfma_f32_16x16x32_bf16(Qh[ks], bh, sf[nf], 0, 0, 0);
                sf[nf] = __builtin_amdgcn_mfma_f32_16x16x32_bf16(Qh[ks], bl, sf[nf], 0, 0, 0);
                sf[nf] = __builtin_amdgcn_mfma_f32_16x16x32_bf16(Ql[ks], bh, sf[nf], 0, 0, 0);
            }
        }
        __syncthreads();

        u16* Ph = sKh + w * 1152;
        u16* Pl = sKl + w * 1152;
        #pragma unroll
        for (int nf = 0; nf < 4; ++nf) {
            #pragma unroll
            for (int rr = 0; rr < 4; ++rr) {
                int rq = qrow0 + lg * 4 + rr;
                int ck = kb + nf * 16 + lr;
                float s = sf[nf][rr];
                float p;
                if (BRANCH == 0) {
                    bool valid = (ck <= rq) && (rq - ck < WIN);
                    p = valid ? __expf(s) : 0.f;
                } else if (BRANCH == 1) {
                    bool valid = rq >= (ck + 1) * RATIO;
                    p = (rq < RATIO) ? 1.f : (valid ? __expf(s) : 0.f);
                } else {
                    bool valid = rq >= tj[nf];
                    p = (rq < tmin) ? 1.f : (valid ? __expf(s) : 0.f);
                }
                lvec[rr] += p;
                u16 ph_ = f2bf(p);
                Ph[(lg * 4 + rr) * 72 + nf * 16 + lr] = ph_;
                Pl[(lg * 4 + rr) * 72 + nf * 16 + lr] = f2bf(p - bf2f(ph_));
            }
        }

        bf16x8 pah[2], pal[2];
        #pragma unroll
        for (int ks2 = 0; ks2 < 2; ++ks2) {
            pah[ks2] = *(const bf16x8*)&Ph[lr * 72 + ks2 * 32 + lg * 8];
            pal[ks2] = *(const bf16x8*)&Pl[lr * 72 + ks2 * 32 + lg * 8];
        }
        #pragma unroll
        for (int nd = 0; nd < 4; ++nd) {
            #pragma unroll
            for (int ks2 = 0; ks2 < 2; ++ks2) {
                bf16x8 vh = *(const bf16x8*)&sVh[(nd * 16 + lr) * 72 + ks2 * 32 + lg * 8];
                bf16x8 vl = *(const bf16x8*)&sVl[(nd * 16 + lr) * 72 + ks2 * 32 + lg * 8];
                onf[nd] = __builtin_amdgcn_mfma_f32_16x16x32_bf16(pah[ks2], vh, onf[nd], 0, 0, 0);
                onf[nd] = __builtin_amdgcn_mfma_f32_16x16x32_bf16(pah[ks2], vl, onf[nd], 0, 0, 0);
                onf[nd] = __builtin_amdgcn_mfma_f32_16x16x32_bf16(pal[ks2], vh, onf[nd], 0, 0, 0);
            }
        }
    }

    #pragma unroll
    for (int bit = 1; bit <= 8; bit <<= 1) {
        lvec[0] += __shfl_xor(lvec[0], bit);
        lvec[1] += __shfl_xor(lvec[1], bit);
        lvec[2] += __shfl_xor(lvec[2], bit);
        lvec[3] += __shfl_xor(lvec[3], bit);
    }
    f32x4 inv;
    #pragma unroll
    for (int rr = 0; rr < 4; ++rr) inv[rr] = 1.0f / lvec[rr];

    const int h = blockIdx.y;
    #pragma unroll
    for (int nd = 0; nd < 4; ++nd) {
        #pragma unroll
        for (int rr = 0; rr < 4; ++rr) {
            int row = b * SEQ + qrow0 + lg * 4 + rr;
            size_t idx = (size_t)row * DM + h * HDIM + nd * 16 + lr;
            float v = onf[nd][rr] * inv[rr];
            u16 hv = f2bf(v);
            oh[idx] = hv;
            ol[idx] = f2bf(v - bf2f(hv));
        }
    }
}

__global__ __launch_bounds__(256)
void attn_all(const u16* __restrict__ qkvh, const u16* __restrict__ qkvl,
              const u16* __restrict__ VTlh, const u16* __restrict__ VTll,
              const u16* __restrict__ fqqh, const u16* __restrict__ fqql,
              const u16* __restrict__ kch, const u16* __restrict__ kcl,
              const u16* __restrict__ vcTh, const u16* __restrict__ vcTl,
              const u16* __restrict__ kth, const u16* __restrict__ ktl,
              const u16* __restrict__ vtTh, const u16* __restrict__ vtTl,
              const int* __restrict__ tidx,
              u16* __restrict__ aLh, u16* __restrict__ aLl,
              u16* __restrict__ aCh, u16* __restrict__ aCl,
              u16* __restrict__ aTh, u16* __restrict__ aTl)
{
    __shared__ __align__(16) u16 sKh[64 * 72], sKl[64 * 72], sVh[64 * 72], sVl[64 * 72];
    const int qb = blockIdx.x, h = blockIdx.y;
    const int branch = blockIdx.z >> 1, b = blockIdx.z & 1;
    const size_t vrow0 = (size_t)(b * 512 + h * HDIM);
    if (branch == 0) {
        attn_body<0>(sKh, sKl, sVh, sVl,
                     qkvh, qkvl, 1536, h * HDIM,
                     qkvh, qkvl, 1536, 512 + h * HDIM, (size_t)b * SEQ,
                     VTlh, VTll, 2048, vrow0,
                     nullptr, aLh, aLl, qb, b);
    } else if (branch == 1) {
        attn_body<1>(sKh, sKl, sVh, sVl,
                     fqqh, fqql, 1024, h * HDIM,
                     kch, kcl, 512, h * HDIM, (size_t)b * NPOOLS,
                     vcTh, vcTl, NPOOLS, vrow0,
                     nullptr, aCh, aCl, qb, b);
    } else {
        attn_body<2>(sKh, sKl, sVh, sVl,
                     fqqh, fqql, 1024, 512 + h * HDIM,
                     kth, ktl, 512, h * HDIM, (size_t)b * TOPKN,
                     vtTh, vtTl, TOPKN, vrow0,
                     tidx, aTh, aTl, qb, b);
    }
}

extern "C" void kernel_launch(void* const* d_in, const int* in_sizes, int n_in,
                              void* d_out, int out_size, void* d_ws, size_t ws_size,
                              hipStream_t stream)
{
    const float* x      = (const float*)d_in[0];
    const float* lqkv_W = (const float*)d_in[1];
    const float* lqkv_b = (const float*)d_in[2];
    const float* lout_W = (const float*)d_in[3];
    const float* lout_b = (const float*)d_in[4];
    const float* cq_W   = (const float*)d_in[5];
    const float* cq_b   = (const float*)d_in[6];
    const float* ck_W   = (const float*)d_in[7];
    const float* ck_b   = (const float*)d_in[8];
    const float* cv_W   = (const float*)d_in[9];
    const float* cv_b   = (const float*)d_in[10];
    const float* cout_W = (const float*)d_in[11];
    const float* cout_b = (const float*)d_in[12];
    const float* gc_W   = (const float*)d_in[13];
    const float* gc_b   = (const float*)d_in[14];
    const float* imp_W  = (const float*)d_in[15];
    const float* imp_b  = (const float*)d_in[16];
    const float* tq_W   = (const float*)d_in[17];
    const float* tq_b   = (const float*)d_in[18];
    const float* tk_W   = (const float*)d_in[19];
    const float* tk_b   = (const float*)d_in[20];
    const float* tv_W   = (const float*)d_in[21];
    const float* tv_b   = (const float*)d_in[22];
    const float* tout_W = (const float*)d_in[23];
    const float* tout_b = (const float*)d_in[24];
    const float* gt_W   = (const float*)d_in[25];
    const float* gt_b   = (const float*)d_in[26];
    float* out = (float*)d_out;

    char* wsb = (char*)d_ws;
    size_t off = 0;
    auto carve = [&](size_t bytes) { void* p = wsb + off; off += (bytes + 255) & ~(size_t)255; return p; };
    u16*   qkvh  = (u16*)  carve(4096ull * 1536 * 2);
    u16*   qkvl  = (u16*)  carve(4096ull * 1536 * 2);
    u16*   fqqh  = (u16*)  carve(4096ull * 1024 * 2);
    u16*   fqql  = (u16*)  carve(4096ull * 1024 * 2);
    float* gates = (float*)carve(4096ull * 1024 * 4);
    // region X: xkv fp32 aliased by the 6 attention-output planes (disjoint lifetimes)
    char*  X     = (char*) carve(4096ull * 2048 * 4);
    float* xkv   = (float*)X;
    u16*   aLh   = (u16*)(X);
    u16*   aLl   = (u16*)(X + 1 * 4194304);
    u16*   aCh   = (u16*)(X + 2 * 4194304);
    u16*   aCl   = (u16*)(X + 3 * 4194304);
    u16*   aTh   = (u16*)(X + 4 * 4194304);
    u16*   aTl   = (u16*)(X + 5 * 4194304);
    u16*   VTlh  = (u16*)  carve(2ull * 512 * 2048 * 2);
    u16*   VTll  = (u16*)  carve(2ull * 512 * 2048 * 2);
    u16*   xh    = (u16*)  carve(4096ull * 512 * 2);
    u16*   xl    = (u16*)  carve(4096ull * 512 * 2);
    u16*   WmegaTh = (u16*)carve(5632ull * 512 * 2);
    u16*   WmegaTl = (u16*)carve(5632ull * 512 * 2);
    u16*   WLoTh = (u16*)  carve(512ull * 512 * 2);
    u16*   WLoTl = (u16*)  carve(512ull * 512 * 2);
    u16*   WCoTh = (u16*)  carve(512ull * 512 * 2);
    u16*   WCoTl = (u16*)  carve(512ull * 512 * 2);
    u16*   WToTh = (u16*)  carve(512ull * 512 * 2);
    u16*   WToTl = (u16*)  carve(512ull * 512 * 2);
    float* bmega = (float*)carve(5632ull * 4);
    u16*   kch   = (u16*)  carve(384ull * 512 * 2);
    u16*   kcl   = (u16*)  carve(384ull * 512 * 2);
    u16*   vcTh  = (u16*)  carve(2ull * 512 * 192 * 2);
    u16*   vcTl  = (u16*)  carve(2ull * 512 * 192 * 2);
    u16*   kth   = (u16*)  carve(128ull * 512 * 2);
    u16*   ktl   = (u16*)  carve(128ull * 512 * 2);
    u16*   vtTh  = (u16*)  carve(2ull * 512 * 64 * 2);
    u16*   vtTl  = (u16*)  carve(2ull * 512 * 64 * 2);
    float* impb  = (float*)carve(4096ull * 4);
    int*   tidx  = (int*)  carve(128ull * 4);

    // ---- conversions ----
    conv_act<<<1024, 256, 0, stream>>>(x, xh, xl, 4096 * 512 / 8);
    conv_wT<<<dim3(24, 8), 256, 0, stream>>>(lqkv_W, 1536, WmegaTh, WmegaTl, 0);
    conv_wT11<<<dim3(8, 8, 11), 256, 0, stream>>>(cq_W, tq_W, gc_W, gt_W, ck_W, cv_W, tk_W, tv_W,
                                                  lout_W, cout_W, tout_W,
                                                  WmegaTh, WmegaTl,
                                                  WLoTh, WLoTl, WCoTh, WCoTl, WToTh, WToTl);
    bcat_mega<<<22, 256, 0, stream>>>(lqkv_b, cq_b, tq_b, gc_b, gt_b, ck_b, cv_b, tk_b, tv_b, bmega);

    // ---- ONE mega projection (qkv | fqq | gates | xkv) ----
    gemm_mega<<<dim3(44, 32), 256, 0, stream>>>(xh, xl, WmegaTh, WmegaTl, bmega,
                                                qkvh, qkvl, fqqh, fqql, gates, xkv);

    // ---- derived operands ----
    transpV<<<dim3(32, 8, 2), 256, 0, stream>>>(qkvh, qkvl, VTlh, VTll);
    gemv_imp<<<1024, 256, 0, stream>>>(x, imp_W, imp_b, impb);
    topk_bitonic<<<2, 1024, 0, stream>>>(impb, tidx);
    pool_kv<<<384, 256, 0, stream>>>(xkv, kch, kcl, vcTh, vcTl);
    gather_kv<<<128, 256, 0, stream>>>(xkv, tidx, kth, ktl, vtTh, vtTl);

    // ---- merged attention (writes a* planes into region X) ----
    attn_all<<<dim3(32, 8, 6), 256, 0, stream>>>(qkvh, qkvl, VTlh, VTll, fqqh, fqql,
                                                 kch, kcl, vcTh, vcTl, kth, ktl, vtTh, vtTl,
                                                 tidx, aLh, aLl, aCh, aCl, aTh, aTl);

    // ---- output projections: out = projL + sig(gC)*projC + sig(gT)*projT ----
    gemm_mfma<0><<<dim3(4, 32), 256, 0, stream>>>(aLh, aLl, WLoTh, WLoTl, lout_b,
                                                  out, nullptr, 0, 512);
    gemm_mfma<1><<<dim3(4, 32), 256, 0, stream>>>(aCh, aCl, WCoTh, WCoTl, cout_b,
                                                  out, gates, 1024, 512);
    gemm_mfma<1><<<dim3(4, 32), 256, 0, stream>>>(aTh, aTl, WToTh, WToTl, tout_b,
                                                  out, gates + 512, 1024, 512);
}